// Round 3
// baseline (13.881 us; speedup 1.0000x reference)
//
#include <hip/hip_runtime.h>

// out[n,c,h,w] = sum over valid (i,j) in 3x3 of max(x[n,c,h,w], thr[c, 3*i+j])
// valid: i=0 iff h<111, i=2 iff h>0 (i=1 always); j=0 iff w<111, j=2 iff w>0.
// (unfold -> max -> fold overlap-add collapses to a pure elementwise op.)
//
// Decomposition: plane = (n,c), 112 rows x 28 float4 = 3136 float4 = 49 waves
// = 7 blocks x 448 threads exactly. One float4 per thread, no loop, no tail.
// plane is block-uniform -> thr[] loads stay scalar (s_load broadcast).

#define WQ 28
#define NH 112

__global__ __launch_bounds__(448) void convblock_kernel(
    const float* __restrict__ x, const float* __restrict__ thr,
    float* __restrict__ out) {
  const int blk = blockIdx.x;
  const int plane = blk / 7;          // scalar: n*64 + c
  const int chunk = blk - plane * 7;  // 0..6 -> 16-row slab
  const int c = plane & 63;

  float t[9];
#pragma unroll
  for (int k = 0; k < 9; ++k) t[k] = thr[c * 9 + k];

  const int tid = threadIdx.x;
  const int hr = tid / WQ;            // 0..15 (one magic-mul div, once)
  const int wq = tid - hr * WQ;       // 0..27
  const int h = chunk * 16 + hr;

  const float4* __restrict__ xin =
      reinterpret_cast<const float4*>(x) + (size_t)plane * (NH * WQ);
  float4* __restrict__ xout =
      reinterpret_cast<float4*>(out) + (size_t)plane * (NH * WQ);

  const float4 v4 = xin[h * WQ + wq];

  const bool rokTop = (h < NH - 1);   // include row i=0
  const bool rokBot = (h > 0);        // include row i=2
  const bool w0 = (wq == 0);          // element 0 has w==0   -> exclude j=2
  const bool wL = (wq == WQ - 1);     // element 3 has w==111 -> exclude j=0

  const float vv[4] = {v4.x, v4.y, v4.z, v4.w};
  float res[4];
#pragma unroll
  for (int e = 0; e < 4; ++e) {
    const float v = vv[e];
    const bool exclJ2 = (e == 0) && w0;   // compile-time false for e=1,2,3
    const bool exclJ0 = (e == 3) && wL;   // compile-time false for e=0,1,2
    float s = 0.0f;
#pragma unroll
    for (int i = 0; i < 3; ++i) {
      const float m0 = fmaxf(v, t[3 * i + 0]);
      const float m1 = fmaxf(v, t[3 * i + 1]);
      const float m2 = fmaxf(v, t[3 * i + 2]);
      float r = m1;
      r += exclJ0 ? 0.0f : m0;
      r += exclJ2 ? 0.0f : m2;
      const bool rok = (i == 0) ? rokTop : (i == 2) ? rokBot : true;
      s += rok ? r : 0.0f;
    }
    res[e] = s;
  }
  xout[h * WQ + wq] = make_float4(res[0], res[1], res[2], res[3]);
}

extern "C" void kernel_launch(void* const* d_in, const int* in_sizes, int n_in,
                              void* d_out, int out_size, void* d_ws, size_t ws_size,
                              hipStream_t stream) {
  const float* x = (const float*)d_in[0];    // (8,64,112,112) f32
  const float* thr = (const float*)d_in[1];  // (64,9) f32
  float* out = (float*)d_out;                // (8,64,112,112) f32

  dim3 grid(512 * 7);  // 8*64 planes, 7 blocks each
  convblock_kernel<<<grid, 448, 0, stream>>>(x, thr, out);
}

// Round 4
// 13.012 us; speedup vs baseline: 1.0669x; 1.0669x over previous
//
#include <hip/hip_runtime.h>

// out[n,c,h,w] = sum over valid (i,j) in 3x3 of max(x[n,c,h,w], thr[c, 3*i+j])
// valid: i=0 iff h<111, i=2 iff h>0 (i=1 always); j=0 iff w<111, j=2 iff w>0.
// (unfold -> max -> fold overlap-add collapses to a pure elementwise op.)
//
// MLP variant: one block per (n,c) plane -> thr stays scalar (s_load).
// 3136 float4/plane = 448 threads x 7 float4, ALL 7 loads issued before any
// compute (112 B outstanding per lane) to maximize memory-level parallelism.

#define WQ 28
#define NH 112
#define PLANE_F4 (NH * WQ)   // 3136
#define TPB 448
#define PER_T 7

__global__ __launch_bounds__(TPB) void convblock_kernel(
    const float* __restrict__ x, const float* __restrict__ thr,
    float* __restrict__ out) {
  const int plane = blockIdx.x;   // n*64 + c  (block-uniform)
  const int c = plane & 63;

  float t[9];
#pragma unroll
  for (int k = 0; k < 9; ++k) t[k] = thr[c * 9 + k];

  const float4* __restrict__ xin =
      reinterpret_cast<const float4*>(x) + (size_t)plane * PLANE_F4;
  float4* __restrict__ xout =
      reinterpret_cast<float4*>(out) + (size_t)plane * PLANE_F4;

  const int tid = threadIdx.x;

  // Issue all 7 loads first — independent, coalesced (1 KB per wave instr).
  float4 v[PER_T];
#pragma unroll
  for (int k = 0; k < PER_T; ++k) v[k] = xin[tid + k * TPB];

#pragma unroll
  for (int k = 0; k < PER_T; ++k) {
    const int idx = tid + k * TPB;
    const int h = idx / WQ;           // 0..111
    const int wq = idx - h * WQ;      // 0..27
    const bool rokTop = (h < NH - 1); // include row i=0
    const bool rokBot = (h > 0);      // include row i=2
    const bool w0 = (wq == 0);        // elem 0 has w==0   -> exclude j=2
    const bool wL = (wq == WQ - 1);   // elem 3 has w==111 -> exclude j=0

    const float vv[4] = {v[k].x, v[k].y, v[k].z, v[k].w};
    float res[4];
#pragma unroll
    for (int e = 0; e < 4; ++e) {
      const float vx = vv[e];
      const bool exclJ2 = (e == 0) && w0;
      const bool exclJ0 = (e == 3) && wL;
      float s = 0.0f;
#pragma unroll
      for (int i = 0; i < 3; ++i) {
        const float m0 = fmaxf(vx, t[3 * i + 0]);
        const float m1 = fmaxf(vx, t[3 * i + 1]);
        const float m2 = fmaxf(vx, t[3 * i + 2]);
        float r = m1;
        r += exclJ0 ? 0.0f : m0;
        r += exclJ2 ? 0.0f : m2;
        const bool rok = (i == 0) ? rokTop : (i == 2) ? rokBot : true;
        s += rok ? r : 0.0f;
      }
      res[e] = s;
    }
    xout[idx] = make_float4(res[0], res[1], res[2], res[3]);
  }
}

extern "C" void kernel_launch(void* const* d_in, const int* in_sizes, int n_in,
                              void* d_out, int out_size, void* d_ws, size_t ws_size,
                              hipStream_t stream) {
  const float* x = (const float*)d_in[0];    // (8,64,112,112) f32
  const float* thr = (const float*)d_in[1];  // (64,9) f32
  float* out = (float*)d_out;                // (8,64,112,112) f32

  convblock_kernel<<<dim3(8 * 64), TPB, 0, stream>>>(x, thr, out);
}